// Round 3
// baseline (1321.061 us; speedup 1.0000x reference)
//
#include <hip/hip_runtime.h>
#include <math.h>

// ---------------------------------------------------------------------------
// QwenMambaLayer fp32 baseline for MI355X.
// Pipeline: rmsnorm -> gemm(in_proj) -> conv1d+silu -> gemm(x_proj, split-K)
//           -> reduce -> gemm(dt_proj)+softplus -> fused selective scan+gate
//           -> gemm(out_proj)+residual.
// All fp32 on the vector ALU (no fp32-input MFMA on CDNA4).
// GEMM K-loop is software-pipelined: global->reg prefetch of tile k+1 issued
// before the FMA block of tile k (G7 latency hiding).
// ---------------------------------------------------------------------------

#define L_SEQ   2048
#define NB      2
#define DMODEL  1024
#define DINNER  2048
#define DSTATE  16
#define DTRANK  64
#define BLROWS  (NB * L_SEQ)   // 4096

__device__ __forceinline__ float silu_(float x) { return x / (1.f + __expf(-x)); }
__device__ __forceinline__ float softplus_(float x) {
  // matches jax.nn.softplus = logaddexp(x, 0), numerically stable
  return fmaxf(x, 0.f) + log1pf(expf(-fabsf(x)));
}

// ---------------- RMSNorm: one block per row of 1024 ----------------
__global__ __launch_bounds__(256) void rmsnorm_k(const float* __restrict__ x,
                                                 const float* __restrict__ w,
                                                 float* __restrict__ xn) {
  const int row = blockIdx.x;
  const float4* xr = (const float4*)(x + (size_t)row * DMODEL);
  float4 v = xr[threadIdx.x];
  float ss = v.x * v.x + v.y * v.y + v.z * v.z + v.w * v.w;
#pragma unroll
  for (int o = 32; o > 0; o >>= 1) ss += __shfl_down(ss, o);
  __shared__ float sred[4];
  const int lane = threadIdx.x & 63, wv = threadIdx.x >> 6;
  if (lane == 0) sred[wv] = ss;
  __syncthreads();
  const float tot = sred[0] + sred[1] + sred[2] + sred[3];
  const float rinv = rsqrtf(tot * (1.f / DMODEL) + 1e-6f);
  const float4 wv4 = ((const float4*)w)[threadIdx.x];
  float4 o;
  o.x = v.x * rinv * wv4.x;
  o.y = v.y * rinv * wv4.y;
  o.z = v.z * rinv * wv4.z;
  o.w = v.w * rinv * wv4.w;
  ((float4*)(xn + (size_t)row * DMODEL))[threadIdx.x] = o;
}

// ---------------- Generic 128x128x16 fp32 tiled GEMM (pipelined) ----------------
// C[M,N] = A[M,K] @ B[K,N]. EPI: 0 plain, 1 softplus(acc+E[n]), 2 acc+E[m*lde+n].
// blockIdx.z split-K: k-range [z*K, (z+1)*K), C offset z*czoff.
template <int EPI, bool NCHECK>
__global__ __launch_bounds__(256)
void gemm_k(const float* __restrict__ A, int lda,
            const float* __restrict__ B, int ldb,
            float* __restrict__ C, int ldc,
            int M, int N, int K, size_t czoff,
            const float* __restrict__ E, int lde) {
  __shared__ float As[16][132];
  __shared__ float Bs[16][132];
  const int tid = threadIdx.x;
  const int tx = tid & 15, ty = tid >> 4;
  const int m0 = blockIdx.y * 128;
  const int n0 = blockIdx.x * 128;
  const int kbase = blockIdx.z * K;
  C += (size_t)blockIdx.z * czoff;

  float acc[8][8];
#pragma unroll
  for (int i = 0; i < 8; ++i)
#pragma unroll
    for (int j = 0; j < 8; ++j) acc[i][j] = 0.f;

  const float* Ap = A + (size_t)m0 * lda + kbase;
  const float* Bp = B + (size_t)kbase * ldb + n0;

  // per-thread staging coordinates
  const int ar0 = (tid + 0) >> 2,   akq0 = ((tid + 0) & 3) << 2;
  const int ar1 = (tid + 256) >> 2, akq1 = ((tid + 256) & 3) << 2;
  const int bkr0 = (tid + 0) >> 5,   bc0 = ((tid + 0) & 31) << 2;
  const int bkr1 = (tid + 256) >> 5, bc1 = ((tid + 256) & 31) << 2;
  const bool bok0 = !NCHECK || (n0 + bc0) < N;
  const bool bok1 = !NCHECK || (n0 + bc1) < N;

  float4 aR0, aR1, bR0, bR1;
  // prologue: load tile kt=0 into regs
  aR0 = *(const float4*)(Ap + (size_t)ar0 * lda + akq0);
  aR1 = *(const float4*)(Ap + (size_t)ar1 * lda + akq1);
  bR0 = bok0 ? *(const float4*)(Bp + (size_t)bkr0 * ldb + bc0)
             : make_float4(0.f, 0.f, 0.f, 0.f);
  bR1 = bok1 ? *(const float4*)(Bp + (size_t)bkr1 * ldb + bc1)
             : make_float4(0.f, 0.f, 0.f, 0.f);

  for (int kt = 0; kt < K; kt += 16) {
    // commit regs -> LDS
    As[akq0 + 0][ar0] = aR0.x; As[akq0 + 1][ar0] = aR0.y;
    As[akq0 + 2][ar0] = aR0.z; As[akq0 + 3][ar0] = aR0.w;
    As[akq1 + 0][ar1] = aR1.x; As[akq1 + 1][ar1] = aR1.y;
    As[akq1 + 2][ar1] = aR1.z; As[akq1 + 3][ar1] = aR1.w;
    *(float4*)&Bs[bkr0][bc0] = bR0;
    *(float4*)&Bs[bkr1][bc1] = bR1;
    __syncthreads();
    // prefetch tile kt+16 into regs (hides global latency under the FMAs)
    if (kt + 16 < K) {
      const int kn = kt + 16;
      aR0 = *(const float4*)(Ap + (size_t)ar0 * lda + kn + akq0);
      aR1 = *(const float4*)(Ap + (size_t)ar1 * lda + kn + akq1);
      if (bok0) bR0 = *(const float4*)(Bp + (size_t)(kn + bkr0) * ldb + bc0);
      if (bok1) bR1 = *(const float4*)(Bp + (size_t)(kn + bkr1) * ldb + bc1);
    }
#pragma unroll
    for (int kk = 0; kk < 16; ++kk) {
      float a[8], b[8];
      {
        const float4 t0 = *(const float4*)&As[kk][ty << 2];
        const float4 t1 = *(const float4*)&As[kk][64 + (ty << 2)];
        a[0] = t0.x; a[1] = t0.y; a[2] = t0.z; a[3] = t0.w;
        a[4] = t1.x; a[5] = t1.y; a[6] = t1.z; a[7] = t1.w;
        const float4 u0 = *(const float4*)&Bs[kk][tx << 2];
        const float4 u1 = *(const float4*)&Bs[kk][64 + (tx << 2)];
        b[0] = u0.x; b[1] = u0.y; b[2] = u0.z; b[3] = u0.w;
        b[4] = u1.x; b[5] = u1.y; b[6] = u1.z; b[7] = u1.w;
      }
#pragma unroll
      for (int i = 0; i < 8; ++i)
#pragma unroll
        for (int j = 0; j < 8; ++j) acc[i][j] = fmaf(a[i], b[j], acc[i][j]);
    }
    __syncthreads();
  }

#pragma unroll
  for (int i = 0; i < 8; ++i) {
    const int m = m0 + ((i >> 2) << 6) + (ty << 2) + (i & 3);
#pragma unroll
    for (int jh = 0; jh < 2; ++jh) {
      const int n = n0 + (jh << 6) + (tx << 2);
      if (NCHECK && n >= N) continue;
      float4 v;
      v.x = acc[i][jh * 4 + 0];
      v.y = acc[i][jh * 4 + 1];
      v.z = acc[i][jh * 4 + 2];
      v.w = acc[i][jh * 4 + 3];
      if (EPI == 1) {
        v.x = softplus_(v.x + E[n + 0]);
        v.y = softplus_(v.y + E[n + 1]);
        v.z = softplus_(v.z + E[n + 2]);
        v.w = softplus_(v.w + E[n + 3]);
      } else if (EPI == 2) {
        const float4 r = *(const float4*)(E + (size_t)m * lde + n);
        v.x += r.x; v.y += r.y; v.z += r.z; v.w += r.w;
      }
      *(float4*)(C + (size_t)m * ldc + n) = v;
    }
  }
}

// ---------------- causal depthwise conv1d + bias + silu ----------------
// in: xz cols [0,2048) (row stride 4096), out: xc [4096][2048]
__global__ __launch_bounds__(256) void conv_silu_k(const float* __restrict__ xz,
                                                   const float* __restrict__ cw,
                                                   const float* __restrict__ cb,
                                                   float* __restrict__ xc) {
  const int idx = blockIdx.x * 256 + threadIdx.x;  // over 4096*2048
  const int d = idx & (DINNER - 1);
  const int bt = idx >> 11;
  const int t = bt & (L_SEQ - 1);
  const int b = bt >> 11;
  const float4 w4 = ((const float4*)cw)[d];  // conv_w[d][0][0..3]
  const float wj[4] = {w4.x, w4.y, w4.z, w4.w};
  float acc = cb[d];
  const float* base = xz + ((size_t)b * L_SEQ) * 4096 + d;
#pragma unroll
  for (int j = 0; j < 4; ++j) {
    const int tt = t - 3 + j;
    if (tt >= 0) acc = fmaf(wj[j], base[(size_t)tt * 4096], acc);
  }
  xc[(size_t)bt * DINNER + d] = acc * (1.f / (1.f + __expf(-acc)));
}

// ---------------- reduce 8 split-K slices of xp ----------------
__global__ __launch_bounds__(256) void reduce8_k(const float* __restrict__ part,
                                                 float* __restrict__ out, int n) {
  const int i = blockIdx.x * 256 + threadIdx.x;
  if (i < n) {
    float s = 0.f;
#pragma unroll
    for (int j = 0; j < 8; ++j) s += part[(size_t)j * n + i];
    out[i] = s;
  }
}

// ---------------- fused selective scan + D-skip + silu(z) gate ----------------
// block: 256 threads = 16 d-channels x 16 states; grid: NB * (DINNER/16) = 256
// reads delta[4096][2048], xc[4096][2048], xp[4096][96] (B at +64, C at +80),
// z = xz[row][2048+d]; writes yg into xz[row][d] (x_ssm cols are dead).
__global__ __launch_bounds__(256) void scan_k(const float* __restrict__ delta,
                                              const float* __restrict__ xc,
                                              const float* __restrict__ xp,
                                              const float* __restrict__ logA,
                                              const float* __restrict__ Dp,
                                              float* __restrict__ xz) {
  const int s = threadIdx.x & 15;
  const int dl = threadIdx.x >> 4;  // 0..15
  const int b = blockIdx.x >> 7;
  const int d0 = (blockIdx.x & 127) * 16;
  const int d = d0 + dl;

  const float Ac = -__expf(logA[(size_t)d * DSTATE + s]);
  const float Dv = Dp[d];

  __shared__ float sdel[64][16];
  __shared__ float sx[64][16];
  __shared__ float sz[64][16];
  __shared__ float sB[64][16];
  __shared__ float sC[64][16];

  float h = 0.f;
  const int rowbase = b * L_SEQ;
  for (int t0 = 0; t0 < L_SEQ; t0 += 64) {
#pragma unroll
    for (int u = 0; u < 4; ++u) {
      const int idx = threadIdx.x + u * 256;  // < 1024
      const int tt = idx >> 4, dd = idx & 15;
      const size_t row = (size_t)(rowbase + t0 + tt);
      sdel[tt][dd] = delta[row * DINNER + d0 + dd];
      sx[tt][dd] = xc[row * DINNER + d0 + dd];
      sz[tt][dd] = xz[row * 4096 + DINNER + d0 + dd];
      sB[tt][dd] = xp[row * 96 + DTRANK + dd];
      sC[tt][dd] = xp[row * 96 + DTRANK + DSTATE + dd];
    }
    __syncthreads();
#pragma unroll 4
    for (int t = 0; t < 64; ++t) {
      const float dv = sdel[t][dl];
      const float xv = sx[t][dl];
      const float dA = __expf(dv * Ac);
      const float dbx = dv * sB[t][s] * xv;
      h = fmaf(dA, h, dbx);
      float yp = h * sC[t][s];
      yp += __shfl_xor(yp, 1);
      yp += __shfl_xor(yp, 2);
      yp += __shfl_xor(yp, 4);
      yp += __shfl_xor(yp, 8);
      if (s == 0) {
        const size_t row = (size_t)(rowbase + t0 + t);
        const float zv = sz[t][dl];
        const float g = zv / (1.f + __expf(-zv));
        xz[row * 4096 + d0 + dl] = (yp + xv * Dv) * g;
      }
    }
    __syncthreads();
  }
}

// ---------------------------------------------------------------------------
extern "C" void kernel_launch(void* const* d_in, const int* in_sizes, int n_in,
                              void* d_out, int out_size, void* d_ws, size_t ws_size,
                              hipStream_t stream) {
  const float* x = (const float*)d_in[0];
  const float* norm_w = (const float*)d_in[1];
  const float* in_w = (const float*)d_in[2];
  const float* conv_w = (const float*)d_in[3];
  const float* conv_b = (const float*)d_in[4];
  const float* xproj_w = (const float*)d_in[5];
  const float* dt_w = (const float*)d_in[6];
  const float* dt_b = (const float*)d_in[7];
  const float* log_A = (const float*)d_in[8];
  const float* D_param = (const float*)d_in[9];
  const float* out_w = (const float*)d_in[10];
  float* out = (float*)d_out;

  float* ws = (float*)d_ws;
  float* xn = ws;                                  // 4096*1024
  float* xz = xn + (size_t)BLROWS * DMODEL;        // 4096*4096
  float* xc = xz + (size_t)BLROWS * 4096;          // 4096*2048
  float* xp_p = xc + (size_t)BLROWS * DINNER;      // 8*4096*96
  float* xp = xp_p + (size_t)8 * BLROWS * 96;      // 4096*96
  float* delta = xp + (size_t)BLROWS * 96;         // 4096*2048
  const size_t need = ((size_t)(delta - ws) + (size_t)BLROWS * DINNER) * 4;
  if (ws_size < need) return;  // fail loudly (validation will catch it)

  // 1. RMSNorm
  rmsnorm_k<<<BLROWS, 256, 0, stream>>>(x, norm_w, xn);
  // 2. in_proj: xz = xn @ in_w   [4096,1024]x[1024,4096]
  gemm_k<0, false><<<dim3(32, 32, 1), 256, 0, stream>>>(
      xn, DMODEL, in_w, 4096, xz, 4096, BLROWS, 4096, DMODEL, 0, nullptr, 0);
  // 3. causal depthwise conv + silu -> xc
  conv_silu_k<<<(BLROWS * DINNER) / 256, 256, 0, stream>>>(xz, conv_w, conv_b, xc);
  // 4. x_proj (skinny N=96): split-K=8 partials
  gemm_k<0, true><<<dim3(1, 32, 8), 256, 0, stream>>>(
      xc, DINNER, xproj_w, 96, xp_p, 96, BLROWS, 96, DINNER / 8,
      (size_t)BLROWS * 96, nullptr, 0);
  reduce8_k<<<(BLROWS * 96) / 256, 256, 0, stream>>>(xp_p, xp, BLROWS * 96);
  // 5. dt_proj + softplus: delta = softplus(xp[:,:64] @ dt_w + dt_b)
  gemm_k<1, false><<<dim3(16, 32, 1), 256, 0, stream>>>(
      xp, 96, dt_w, DINNER, delta, DINNER, BLROWS, DINNER, DTRANK, 0, dt_b, 0);
  // 6. fused selective scan + gate; writes y*silu(z) into xz cols [0,2048)
  scan_k<<<NB * (DINNER / 16), 256, 0, stream>>>(delta, xc, xp, log_A, D_param, xz);
  // 7. out_proj + residual: out = x + yg @ out_w
  gemm_k<2, false><<<dim3(8, 32, 1), 256, 0, stream>>>(
      xz, 4096, out_w, DMODEL, out, DMODEL, BLROWS, DMODEL, DINNER, 0, x, DMODEL);
}

// Round 6
// 868.963 us; speedup vs baseline: 1.5203x; 1.5203x over previous
//
#include <hip/hip_runtime.h>
#include <math.h>

// ---------------------------------------------------------------------------
// QwenMambaLayer fp32 for MI355X.
// rmsnorm -> gemm(in_proj) -> conv1d+silu -> gemm(x_proj split-K) -> reduce
//   -> gemm(dt_proj)+softplus -> CHUNKED 2-PASS selective scan
//   -> gemm(out_proj split-K=4) -> reduce4+residual.
// Round-3 profile: scan_k 517us at 1 wave/SIMD (latency-bound) -> chunked scan;
// out_proj was 256 blocks = 1 block/CU -> split-K=4 for 4x block parallelism.
// ---------------------------------------------------------------------------

#define L_SEQ   2048
#define NB      2
#define DMODEL  1024
#define DINNER  2048
#define DSTATE  16
#define DTRANK  64
#define BLROWS  (NB * L_SEQ)   // 4096
#define NC      32             // L-chunks for the scan
#define CL      (L_SEQ / NC)   // 64 rows per chunk

__device__ __forceinline__ float silu_(float x) { return x / (1.f + __expf(-x)); }
__device__ __forceinline__ float softplus_(float x) {
  return fmaxf(x, 0.f) + log1pf(expf(-fabsf(x)));
}

// ---------------- RMSNorm: one block per row of 1024 ----------------
__global__ __launch_bounds__(256) void rmsnorm_k(const float* __restrict__ x,
                                                 const float* __restrict__ w,
                                                 float* __restrict__ xn) {
  const int row = blockIdx.x;
  const float4* xr = (const float4*)(x + (size_t)row * DMODEL);
  float4 v = xr[threadIdx.x];
  float ss = v.x * v.x + v.y * v.y + v.z * v.z + v.w * v.w;
#pragma unroll
  for (int o = 32; o > 0; o >>= 1) ss += __shfl_down(ss, o);
  __shared__ float sred[4];
  const int lane = threadIdx.x & 63, wv = threadIdx.x >> 6;
  if (lane == 0) sred[wv] = ss;
  __syncthreads();
  const float tot = sred[0] + sred[1] + sred[2] + sred[3];
  const float rinv = rsqrtf(tot * (1.f / DMODEL) + 1e-6f);
  const float4 wv4 = ((const float4*)w)[threadIdx.x];
  float4 o;
  o.x = v.x * rinv * wv4.x;
  o.y = v.y * rinv * wv4.y;
  o.z = v.z * rinv * wv4.z;
  o.w = v.w * rinv * wv4.w;
  ((float4*)(xn + (size_t)row * DMODEL))[threadIdx.x] = o;
}

// ---------------- Generic 128x128x16 fp32 tiled GEMM (pipelined) ----------------
// C[M,N] = A[M,K] @ B[K,N]. EPI: 0 plain, 1 softplus(acc+E[n]), 2 acc+E[m*lde+n].
template <int EPI, bool NCHECK>
__global__ __launch_bounds__(256)
void gemm_k(const float* __restrict__ A, int lda,
            const float* __restrict__ B, int ldb,
            float* __restrict__ C, int ldc,
            int M, int N, int K, size_t czoff,
            const float* __restrict__ E, int lde) {
  __shared__ float As[16][132];
  __shared__ float Bs[16][132];
  const int tid = threadIdx.x;
  const int tx = tid & 15, ty = tid >> 4;
  const int m0 = blockIdx.y * 128;
  const int n0 = blockIdx.x * 128;
  const int kbase = blockIdx.z * K;
  C += (size_t)blockIdx.z * czoff;

  float acc[8][8];
#pragma unroll
  for (int i = 0; i < 8; ++i)
#pragma unroll
    for (int j = 0; j < 8; ++j) acc[i][j] = 0.f;

  const float* Ap = A + (size_t)m0 * lda + kbase;
  const float* Bp = B + (size_t)kbase * ldb + n0;

  const int ar0 = (tid + 0) >> 2,   akq0 = ((tid + 0) & 3) << 2;
  const int ar1 = (tid + 256) >> 2, akq1 = ((tid + 256) & 3) << 2;
  const int bkr0 = (tid + 0) >> 5,   bc0 = ((tid + 0) & 31) << 2;
  const int bkr1 = (tid + 256) >> 5, bc1 = ((tid + 256) & 31) << 2;
  const bool bok0 = !NCHECK || (n0 + bc0) < N;
  const bool bok1 = !NCHECK || (n0 + bc1) < N;

  float4 aR0, aR1, bR0, bR1;
  aR0 = *(const float4*)(Ap + (size_t)ar0 * lda + akq0);
  aR1 = *(const float4*)(Ap + (size_t)ar1 * lda + akq1);
  bR0 = bok0 ? *(const float4*)(Bp + (size_t)bkr0 * ldb + bc0)
             : make_float4(0.f, 0.f, 0.f, 0.f);
  bR1 = bok1 ? *(const float4*)(Bp + (size_t)bkr1 * ldb + bc1)
             : make_float4(0.f, 0.f, 0.f, 0.f);

  for (int kt = 0; kt < K; kt += 16) {
    As[akq0 + 0][ar0] = aR0.x; As[akq0 + 1][ar0] = aR0.y;
    As[akq0 + 2][ar0] = aR0.z; As[akq0 + 3][ar0] = aR0.w;
    As[akq1 + 0][ar1] = aR1.x; As[akq1 + 1][ar1] = aR1.y;
    As[akq1 + 2][ar1] = aR1.z; As[akq1 + 3][ar1] = aR1.w;
    *(float4*)&Bs[bkr0][bc0] = bR0;
    *(float4*)&Bs[bkr1][bc1] = bR1;
    __syncthreads();
    if (kt + 16 < K) {
      const int kn = kt + 16;
      aR0 = *(const float4*)(Ap + (size_t)ar0 * lda + kn + akq0);
      aR1 = *(const float4*)(Ap + (size_t)ar1 * lda + kn + akq1);
      if (bok0) bR0 = *(const float4*)(Bp + (size_t)(kn + bkr0) * ldb + bc0);
      if (bok1) bR1 = *(const float4*)(Bp + (size_t)(kn + bkr1) * ldb + bc1);
    }
#pragma unroll
    for (int kk = 0; kk < 16; ++kk) {
      float a[8], b[8];
      {
        const float4 t0 = *(const float4*)&As[kk][ty << 2];
        const float4 t1 = *(const float4*)&As[kk][64 + (ty << 2)];
        a[0] = t0.x; a[1] = t0.y; a[2] = t0.z; a[3] = t0.w;
        a[4] = t1.x; a[5] = t1.y; a[6] = t1.z; a[7] = t1.w;
        const float4 u0 = *(const float4*)&Bs[kk][tx << 2];
        const float4 u1 = *(const float4*)&Bs[kk][64 + (tx << 2)];
        b[0] = u0.x; b[1] = u0.y; b[2] = u0.z; b[3] = u0.w;
        b[4] = u1.x; b[5] = u1.y; b[6] = u1.z; b[7] = u1.w;
      }
#pragma unroll
      for (int i = 0; i < 8; ++i)
#pragma unroll
        for (int j = 0; j < 8; ++j) acc[i][j] = fmaf(a[i], b[j], acc[i][j]);
    }
    __syncthreads();
  }

#pragma unroll
  for (int i = 0; i < 8; ++i) {
    const int m = m0 + ((i >> 2) << 6) + (ty << 2) + (i & 3);
#pragma unroll
    for (int jh = 0; jh < 2; ++jh) {
      const int n = n0 + (jh << 6) + (tx << 2);
      if (NCHECK && n >= N) continue;
      float4 v;
      v.x = acc[i][jh * 4 + 0];
      v.y = acc[i][jh * 4 + 1];
      v.z = acc[i][jh * 4 + 2];
      v.w = acc[i][jh * 4 + 3];
      if (EPI == 1) {
        v.x = softplus_(v.x + E[n + 0]);
        v.y = softplus_(v.y + E[n + 1]);
        v.z = softplus_(v.z + E[n + 2]);
        v.w = softplus_(v.w + E[n + 3]);
      } else if (EPI == 2) {
        const float4 r = *(const float4*)(E + (size_t)m * lde + n);
        v.x += r.x; v.y += r.y; v.z += r.z; v.w += r.w;
      }
      *(float4*)(C + (size_t)m * ldc + n) = v;
    }
  }
}

// ---------------- causal depthwise conv1d + bias + silu ----------------
__global__ __launch_bounds__(256) void conv_silu_k(const float* __restrict__ xz,
                                                   const float* __restrict__ cw,
                                                   const float* __restrict__ cb,
                                                   float* __restrict__ xc) {
  const int idx = blockIdx.x * 256 + threadIdx.x;
  const int d = idx & (DINNER - 1);
  const int bt = idx >> 11;
  const int t = bt & (L_SEQ - 1);
  const int b = bt >> 11;
  const float4 w4 = ((const float4*)cw)[d];
  const float wj[4] = {w4.x, w4.y, w4.z, w4.w};
  float acc = cb[d];
  const float* base = xz + ((size_t)b * L_SEQ) * 4096 + d;
#pragma unroll
  for (int j = 0; j < 4; ++j) {
    const int tt = t - 3 + j;
    if (tt >= 0) acc = fmaf(wj[j], base[(size_t)tt * 4096], acc);
  }
  xc[(size_t)bt * DINNER + d] = acc * (1.f / (1.f + __expf(-acc)));
}

// ---------------- reduce 8 split-K slices of xp ----------------
__global__ __launch_bounds__(256) void reduce8_k(const float* __restrict__ part,
                                                 float* __restrict__ out, int n) {
  const int i = blockIdx.x * 256 + threadIdx.x;
  if (i < n) {
    float s = 0.f;
#pragma unroll
    for (int j = 0; j < 8; ++j) s += part[(size_t)j * n + i];
    out[i] = s;
  }
}

// ---------------- reduce 4 split-K slices + residual (out_proj) ----------------
// out[i] = resid[i] + sum_j part[j][i], float4-vectorized over BLROWS*DMODEL.
__global__ __launch_bounds__(256) void reduce4res_k(const float* __restrict__ part,
                                                    const float* __restrict__ resid,
                                                    float* __restrict__ out) {
  const size_t i = (size_t)blockIdx.x * 256 + threadIdx.x;  // float4 index
  const size_t n4 = (size_t)BLROWS * DMODEL / 4;
  const float4* p = (const float4*)part;
  const float4 r = ((const float4*)resid)[i];
  const float4 a = p[i];
  const float4 b = p[i + n4];
  const float4 c = p[i + 2 * n4];
  const float4 d = p[i + 3 * n4];
  float4 o;
  o.x = r.x + ((a.x + b.x) + (c.x + d.x));
  o.y = r.y + ((a.y + b.y) + (c.y + d.y));
  o.z = r.z + ((a.z + b.z) + (c.z + d.z));
  o.w = r.w + ((a.w + b.w) + (c.w + d.w));
  ((float4*)out)[i] = o;
}

// ======================= chunked 2-pass selective scan ======================
// Wave-task decode: w in [0,2048): dg = w&31 (d-group of 64), c = (w>>5)&31
// (L-chunk), b = w>>10. lane owns channel d = dg*64+lane; h[16] in registers.
// hend/hin layout: [b][c][s][d] (coalesced in d). sumdv: [b][c][d].

// ---- pass 1: per-chunk local scan (h_in = 0) + sum(delta) ----
__global__ __launch_bounds__(256) void scan_p1(const float* __restrict__ delta,
                                               const float* __restrict__ xc,
                                               const float* __restrict__ xp,
                                               const float* __restrict__ logA,
                                               float* __restrict__ hend,
                                               float* __restrict__ sumdv) {
  const int w = blockIdx.x * 4 + (threadIdx.x >> 6);
  const int lane = threadIdx.x & 63;
  const int dg = w & 31, c = (w >> 5) & 31, b = w >> 10;
  const int d = dg * 64 + lane;

  float A_[16];
#pragma unroll
  for (int s = 0; s < 16; ++s) A_[s] = -__expf(logA[d * 16 + s]);
  float h[16];
#pragma unroll
  for (int s = 0; s < 16; ++s) h[s] = 0.f;
  float sdv = 0.f;

  const int row0 = b * L_SEQ + c * CL;
  const float* dp = delta + (size_t)row0 * DINNER + d;
  const float* xq = xc + (size_t)row0 * DINNER + d;
  const float* bp = xp + (size_t)row0 * 96 + DTRANK;

  float dv_n = *dp, xv_n = *xq;
  float4 B0 = *(const float4*)(bp + 0), B1 = *(const float4*)(bp + 4);
  float4 B2 = *(const float4*)(bp + 8), B3 = *(const float4*)(bp + 12);

  for (int t = 0; t < CL; ++t) {
    const float dv = dv_n, xv = xv_n;
    const float Bs[16] = {B0.x, B0.y, B0.z, B0.w, B1.x, B1.y, B1.z, B1.w,
                          B2.x, B2.y, B2.z, B2.w, B3.x, B3.y, B3.z, B3.w};
    if (t + 1 < CL) {
      dp += DINNER; xq += DINNER; bp += 96;
      dv_n = *dp; xv_n = *xq;
      B0 = *(const float4*)(bp + 0); B1 = *(const float4*)(bp + 4);
      B2 = *(const float4*)(bp + 8); B3 = *(const float4*)(bp + 12);
    }
    const float dxv = dv * xv;
    sdv += dv;
#pragma unroll
    for (int s = 0; s < 16; ++s) {
      const float dA = __expf(dv * A_[s]);
      h[s] = fmaf(dA, h[s], dxv * Bs[s]);
    }
  }
  const size_t bc = (size_t)(b * NC + c);
#pragma unroll
  for (int s = 0; s < 16; ++s) hend[(bc * 16 + s) * DINNER + d] = h[s];
  sumdv[bc * DINNER + d] = sdv;
}

// ---- mid: chain the 32 chunk states per (b,d,s) ----
__global__ __launch_bounds__(256) void scan_mid(const float* __restrict__ hend,
                                                const float* __restrict__ sumdv,
                                                const float* __restrict__ logA,
                                                float* __restrict__ hin) {
  const int tid = blockIdx.x * 256 + threadIdx.x;
  const int d = tid & (DINNER - 1);
  const int s = (tid >> 11) & 15;
  const int b = tid >> 15;
  const float A = -__expf(logA[d * 16 + s]);
  float hr = 0.f;
  for (int c = 0; c < NC; ++c) {
    const size_t bc = (size_t)(b * NC + c);
    const size_t o = (bc * 16 + s) * DINNER + d;
    hin[o] = hr;
    const float P = __expf(A * sumdv[bc * DINNER + d]);
    hr = fmaf(P, hr, hend[o]);
  }
}

// ---- pass 2: full scan per chunk with correct h_in, y += x*D, gate silu(z) ----
__global__ __launch_bounds__(256) void scan_p2(const float* __restrict__ delta,
                                               const float* __restrict__ xc,
                                               const float* __restrict__ xp,
                                               const float* __restrict__ logA,
                                               const float* __restrict__ Dp,
                                               const float* __restrict__ hin,
                                               const float* __restrict__ zin,
                                               float* __restrict__ yout) {
  const int w = blockIdx.x * 4 + (threadIdx.x >> 6);
  const int lane = threadIdx.x & 63;
  const int dg = w & 31, c = (w >> 5) & 31, b = w >> 10;
  const int d = dg * 64 + lane;

  float A_[16];
#pragma unroll
  for (int s = 0; s < 16; ++s) A_[s] = -__expf(logA[d * 16 + s]);
  const size_t bc = (size_t)(b * NC + c);
  float h[16];
#pragma unroll
  for (int s = 0; s < 16; ++s) h[s] = hin[(bc * 16 + s) * DINNER + d];
  const float Dv = Dp[d];

  const int row0 = b * L_SEQ + c * CL;
  const float* dp = delta + (size_t)row0 * DINNER + d;
  const float* xq = xc + (size_t)row0 * DINNER + d;
  const float* bp = xp + (size_t)row0 * 96 + DTRANK;
  const float* zp = zin + (size_t)row0 * 4096 + d;
  float* yo = yout + (size_t)row0 * 4096 + d;

  float dv_n = *dp, xv_n = *xq, zv_n = *zp;
  float4 B0 = *(const float4*)(bp + 0), B1 = *(const float4*)(bp + 4);
  float4 B2 = *(const float4*)(bp + 8), B3 = *(const float4*)(bp + 12);
  float4 C0 = *(const float4*)(bp + 16), C1 = *(const float4*)(bp + 20);
  float4 C2 = *(const float4*)(bp + 24), C3 = *(const float4*)(bp + 28);

  for (int t = 0; t < CL; ++t) {
    const float dv = dv_n, xv = xv_n, zv = zv_n;
    const float Bs[16] = {B0.x, B0.y, B0.z, B0.w, B1.x, B1.y, B1.z, B1.w,
                          B2.x, B2.y, B2.z, B2.w, B3.x, B3.y, B3.z, B3.w};
    const float Cs[16] = {C0.x, C0.y, C0.z, C0.w, C1.x, C1.y, C1.z, C1.w,
                          C2.x, C2.y, C2.z, C2.w, C3.x, C3.y, C3.z, C3.w};
    if (t + 1 < CL) {
      dp += DINNER; xq += DINNER; bp += 96; zp += 4096;
      dv_n = *dp; xv_n = *xq; zv_n = *zp;
      B0 = *(const float4*)(bp + 0); B1 = *(const float4*)(bp + 4);
      B2 = *(const float4*)(bp + 8); B3 = *(const float4*)(bp + 12);
      C0 = *(const float4*)(bp + 16); C1 = *(const float4*)(bp + 20);
      C2 = *(const float4*)(bp + 24); C3 = *(const float4*)(bp + 28);
    }
    const float dxv = dv * xv;
    float y = xv * Dv;
#pragma unroll
    for (int s = 0; s < 16; ++s) {
      const float dA = __expf(dv * A_[s]);
      h[s] = fmaf(dA, h[s], dxv * Bs[s]);
      y = fmaf(h[s], Cs[s], y);
    }
    const float g = zv / (1.f + __expf(-zv));
    *yo = y * g;
    yo += 4096;
  }
}

// ---------------------------------------------------------------------------
extern "C" void kernel_launch(void* const* d_in, const int* in_sizes, int n_in,
                              void* d_out, int out_size, void* d_ws, size_t ws_size,
                              hipStream_t stream) {
  const float* x = (const float*)d_in[0];
  const float* norm_w = (const float*)d_in[1];
  const float* in_w = (const float*)d_in[2];
  const float* conv_w = (const float*)d_in[3];
  const float* conv_b = (const float*)d_in[4];
  const float* xproj_w = (const float*)d_in[5];
  const float* dt_w = (const float*)d_in[6];
  const float* dt_b = (const float*)d_in[7];
  const float* log_A = (const float*)d_in[8];
  const float* D_param = (const float*)d_in[9];
  const float* out_w = (const float*)d_in[10];
  float* out = (float*)d_out;

  float* ws = (float*)d_ws;
  float* xn = ws;                                  // 4096*1024 (dead after in_proj)
  float* xz = xn + (size_t)BLROWS * DMODEL;        // 4096*4096
  float* xc = xz + (size_t)BLROWS * 4096;          // 4096*2048
  float* xp_p = xc + (size_t)BLROWS * DINNER;      // 8*4096*96 (dead after reduce8)
  float* xp = xp_p + (size_t)8 * BLROWS * 96;      // 4096*96
  float* delta = xp + (size_t)BLROWS * 96;         // 4096*2048
  const size_t need = ((size_t)(delta - ws) + (size_t)BLROWS * DINNER) * 4;
  if (ws_size < need) return;

  // scan chunk-state buffers alias dead regions (no extra ws):
  float* hend = xn;                                // 2*32*16*2048 = 2.10M <= 4.19M
  float* hin = xp_p;                               // 2.10M <= 3.15M
  float* sumdv = xp_p + (size_t)2 * NC * 16 * DINNER;  // 131K, fits remainder
  // out_proj split-K partials: 4*4096*1024 = 16.78M floats; alias xc..delta
  // span (20.3M floats), all dead after scan_p2. xz (A input) is disjoint.
  float* part = xc;

  // 1. RMSNorm
  rmsnorm_k<<<BLROWS, 256, 0, stream>>>(x, norm_w, xn);
  // 2. in_proj
  gemm_k<0, false><<<dim3(32, 32, 1), 256, 0, stream>>>(
      xn, DMODEL, in_w, 4096, xz, 4096, BLROWS, 4096, DMODEL, 0, nullptr, 0);
  // 3. conv + silu
  conv_silu_k<<<(BLROWS * DINNER) / 256, 256, 0, stream>>>(xz, conv_w, conv_b, xc);
  // 4. x_proj split-K=8
  gemm_k<0, true><<<dim3(1, 32, 8), 256, 0, stream>>>(
      xc, DINNER, xproj_w, 96, xp_p, 96, BLROWS, 96, DINNER / 8,
      (size_t)BLROWS * 96, nullptr, 0);
  reduce8_k<<<(BLROWS * 96) / 256, 256, 0, stream>>>(xp_p, xp, BLROWS * 96);
  // 5. dt_proj + softplus
  gemm_k<1, false><<<dim3(16, 32, 1), 256, 0, stream>>>(
      xp, 96, dt_w, DINNER, delta, DINNER, BLROWS, DINNER, DTRANK, 0, dt_b, 0);
  // 6. chunked scan: p1 (local) -> mid (chain) -> p2 (final + gate)
  scan_p1<<<512, 256, 0, stream>>>(delta, xc, xp, log_A, hend, sumdv);
  scan_mid<<<256, 256, 0, stream>>>(hend, sumdv, log_A, hin);
  scan_p2<<<512, 256, 0, stream>>>(delta, xc, xp, log_A, D_param, hin,
                                   xz + DINNER, xz);
  // 7. out_proj split-K=4 (1024 blocks vs 256: fixes 1-block/CU starvation)
  gemm_k<0, false><<<dim3(8, 32, 4), 256, 0, stream>>>(
      xz, 4096, out_w, DMODEL, part, DMODEL, BLROWS, DMODEL, DINNER / 4,
      (size_t)BLROWS * DMODEL, nullptr, 0);
  // 8. sum 4 partials + residual
  reduce4res_k<<<(BLROWS * DMODEL) / 1024, 256, 0, stream>>>(part, x, out);
}

// Round 7
// 478.077 us; speedup vs baseline: 2.7633x; 1.8176x over previous
//
#include <hip/hip_runtime.h>
#include <hip/hip_bf16.h>
#include <math.h>

// ---------------------------------------------------------------------------
// QwenMambaLayer for MI355X.
// rmsnorm(+bf16 split) -> MFMA split-bf16 gemm(in_proj) -> conv1d+silu
//   -> fp32 gemm(x_proj split-K) -> reduce -> fp32 gemm(dt_proj)+softplus
//   -> chunked 2-pass scan (p2 emits bf16-split y) -> MFMA split-bf16
//   gemm(out_proj)+residual.
// Round-6 profile: in_proj fp32 gemm 415us @ 68% VALUBusy (fp32 floor 218us,
// MfmaUtil 0). Split-bf16 (3xMFMA, fp32 acc, ~2^-16 rel err) moves the two
// big GEMMs to the matrix cores (2.5 PF dense vs 157 TF vector).
// ---------------------------------------------------------------------------

#define L_SEQ   2048
#define NB      2
#define DMODEL  1024
#define DINNER  2048
#define DSTATE  16
#define DTRANK  64
#define BLROWS  (NB * L_SEQ)   // 4096
#define NC      32             // L-chunks for the scan
#define CL      (L_SEQ / NC)   // 64 rows per chunk

typedef unsigned short u16;
typedef __attribute__((ext_vector_type(8))) short short8v;   // 8 bf16 = 4 VGPR
typedef __attribute__((ext_vector_type(16))) float f32x16;

__device__ __forceinline__ float softplus_(float x) {
  return fmaxf(x, 0.f) + log1pf(expf(-fabsf(x)));
}
__device__ __forceinline__ void bsplit(float v, u16& h, u16& l) {
  __hip_bfloat16 bh = __float2bfloat16(v);
  float fh = __bfloat162float(bh);
  __hip_bfloat16 bl = __float2bfloat16(v - fh);
  h = *(u16*)&bh; l = *(u16*)&bl;
}

// ---------------- RMSNorm + bf16 hi/lo split ----------------
__global__ __launch_bounds__(256) void rmsnorm_split_k(const float* __restrict__ x,
                                                       const float* __restrict__ w,
                                                       u16* __restrict__ xnh,
                                                       u16* __restrict__ xnl) {
  const int row = blockIdx.x;
  const float4* xr = (const float4*)(x + (size_t)row * DMODEL);
  float4 v = xr[threadIdx.x];
  float ss = v.x * v.x + v.y * v.y + v.z * v.z + v.w * v.w;
#pragma unroll
  for (int o = 32; o > 0; o >>= 1) ss += __shfl_down(ss, o);
  __shared__ float sred[4];
  const int lane = threadIdx.x & 63, wv = threadIdx.x >> 6;
  if (lane == 0) sred[wv] = ss;
  __syncthreads();
  const float tot = sred[0] + sred[1] + sred[2] + sred[3];
  const float rinv = rsqrtf(tot * (1.f / DMODEL) + 1e-6f);
  const float4 wv4 = ((const float4*)w)[threadIdx.x];
  float o[4] = {v.x * rinv * wv4.x, v.y * rinv * wv4.y,
                v.z * rinv * wv4.z, v.w * rinv * wv4.w};
  u16 h[4], lo[4];
#pragma unroll
  for (int i = 0; i < 4; ++i) bsplit(o[i], h[i], lo[i]);
  uint2 ph, pl;
  ph.x = (unsigned)h[0] | ((unsigned)h[1] << 16);
  ph.y = (unsigned)h[2] | ((unsigned)h[3] << 16);
  pl.x = (unsigned)lo[0] | ((unsigned)lo[1] << 16);
  pl.y = (unsigned)lo[2] | ((unsigned)lo[3] << 16);
  *(uint2*)(xnh + (size_t)row * DMODEL + threadIdx.x * 4) = ph;
  *(uint2*)(xnl + (size_t)row * DMODEL + threadIdx.x * 4) = pl;
}

// ---------------- transpose + bf16 split: src[R][C] -> dst[C][R] ----------------
__global__ __launch_bounds__(256) void tsplit_k(const float* __restrict__ src,
                                                int R, int C,
                                                u16* __restrict__ dh,
                                                u16* __restrict__ dl) {
  __shared__ float tile[32][33];
  const int tx = threadIdx.x & 31, ty = threadIdx.x >> 5;
  const int r0 = blockIdx.y * 32, c0 = blockIdx.x * 32;
#pragma unroll
  for (int i = 0; i < 4; ++i)
    tile[ty + i * 8][tx] = src[(size_t)(r0 + ty + i * 8) * C + c0 + tx];
  __syncthreads();
#pragma unroll
  for (int i = 0; i < 4; ++i) {
    const float v = tile[tx][ty + i * 8];
    u16 h, l; bsplit(v, h, l);
    const size_t o = (size_t)(c0 + ty + i * 8) * R + r0 + tx;
    dh[o] = h; dl[o] = l;
  }
}

// ---------------- split-bf16 MFMA GEMM ----------------
// C[M,N] (+E residual if EPI==2) = (Ah+Al)[M,K] @ (Bh+Bl)[K,N], 3-term split.
// A stored [M][K] bf16 row-major (lda); B PRE-TRANSPOSED [N][K] bf16 (ldb).
// Block tile BM x BN, BK=32; wave grid GM x GN, FM x FN 32x32 frags per wave.
template <int GM, int GN, int FM, int FN, int EPI>
__global__ __launch_bounds__(GM * GN * 64)
void mgemm_k(const u16* __restrict__ Ah, const u16* __restrict__ Al, int lda,
             const u16* __restrict__ Bh, const u16* __restrict__ Bl, int ldb,
             float* __restrict__ C, int ldc,
             const float* __restrict__ E, int lde, int K) {
  constexpr int BM = GM * FM * 32, BN = GN * FN * 32, T = GM * GN * 64;
  constexpr int AV = (BM * 4) / T, BV = (BN * 4) / T;
  static_assert((BM * 4) % T == 0 && (BN * 4) % T == 0, "staging divisibility");
  __shared__ __align__(16) u16 smem[(BM + BN) * 64];
  u16* sAh = smem;
  u16* sAl = smem + BM * 32;
  u16* sBh = smem + BM * 64;
  u16* sBl = smem + BM * 64 + BN * 32;

  const int tid = threadIdx.x;
  const int l = tid & 63;
  const int wv = tid >> 6;
  const int wm = wv / GN, wn = wv % GN;
  const int m0 = blockIdx.y * BM, n0 = blockIdx.x * BN;

  f32x16 acc[FM][FN];
#pragma unroll
  for (int i = 0; i < FM; ++i)
#pragma unroll
    for (int j = 0; j < FN; ++j)
#pragma unroll
      for (int e = 0; e < 16; ++e) acc[i][j][e] = 0.f;

  short8v pah[AV], pal[AV], pbh[BV], pbl[BV];
#pragma unroll
  for (int u = 0; u < AV; ++u) {
    const int li = tid + u * T, r = li >> 2, ks = li & 3;
    pah[u] = *(const short8v*)(Ah + (size_t)(m0 + r) * lda + ks * 8);
    pal[u] = *(const short8v*)(Al + (size_t)(m0 + r) * lda + ks * 8);
  }
#pragma unroll
  for (int u = 0; u < BV; ++u) {
    const int li = tid + u * T, r = li >> 2, ks = li & 3;
    pbh[u] = *(const short8v*)(Bh + (size_t)(n0 + r) * ldb + ks * 8);
    pbl[u] = *(const short8v*)(Bl + (size_t)(n0 + r) * ldb + ks * 8);
  }

  const int nk = K >> 5;
  for (int kt = 0; kt < nk; ++kt) {
#pragma unroll
    for (int u = 0; u < AV; ++u) {
      const int li = tid + u * T, r = li >> 2, ks = li & 3;
      const int off = r * 32 + ((ks ^ (r & 3)) << 3);  // XOR swizzle, 16B slots
      *(short8v*)(sAh + off) = pah[u];
      *(short8v*)(sAl + off) = pal[u];
    }
#pragma unroll
    for (int u = 0; u < BV; ++u) {
      const int li = tid + u * T, r = li >> 2, ks = li & 3;
      const int off = r * 32 + ((ks ^ (r & 3)) << 3);
      *(short8v*)(sBh + off) = pbh[u];
      *(short8v*)(sBl + off) = pbl[u];
    }
    __syncthreads();
    if (kt + 1 < nk) {  // reg prefetch of next K-tile (hides global latency)
      const int ko = (kt + 1) * 32;
#pragma unroll
      for (int u = 0; u < AV; ++u) {
        const int li = tid + u * T, r = li >> 2, ks = li & 3;
        pah[u] = *(const short8v*)(Ah + (size_t)(m0 + r) * lda + ko + ks * 8);
        pal[u] = *(const short8v*)(Al + (size_t)(m0 + r) * lda + ko + ks * 8);
      }
#pragma unroll
      for (int u = 0; u < BV; ++u) {
        const int li = tid + u * T, r = li >> 2, ks = li & 3;
        pbh[u] = *(const short8v*)(Bh + (size_t)(n0 + r) * ldb + ko + ks * 8);
        pbl[u] = *(const short8v*)(Bl + (size_t)(n0 + r) * ldb + ko + ks * 8);
      }
    }
#pragma unroll
    for (int ks2 = 0; ks2 < 2; ++ks2) {
      const int kslot = ks2 * 2 + (l >> 5);
      short8v afh[FM], afl[FM], bfh[FN], bfl[FN];
#pragma unroll
      for (int fm = 0; fm < FM; ++fm) {
        const int r = wm * FM * 32 + fm * 32 + (l & 31);
        const int off = r * 32 + ((kslot ^ (r & 3)) << 3);
        afh[fm] = *(const short8v*)(sAh + off);
        afl[fm] = *(const short8v*)(sAl + off);
      }
#pragma unroll
      for (int fn = 0; fn < FN; ++fn) {
        const int r = wn * FN * 32 + fn * 32 + (l & 31);
        const int off = r * 32 + ((kslot ^ (r & 3)) << 3);
        bfh[fn] = *(const short8v*)(sBh + off);
        bfl[fn] = *(const short8v*)(sBl + off);
      }
#pragma unroll
      for (int fm = 0; fm < FM; ++fm)
#pragma unroll
        for (int fn = 0; fn < FN; ++fn) {
          acc[fm][fn] = __builtin_amdgcn_mfma_f32_32x32x16_bf16(
              afh[fm], bfh[fn], acc[fm][fn], 0, 0, 0);
          acc[fm][fn] = __builtin_amdgcn_mfma_f32_32x32x16_bf16(
              afh[fm], bfl[fn], acc[fm][fn], 0, 0, 0);
          acc[fm][fn] = __builtin_amdgcn_mfma_f32_32x32x16_bf16(
              afl[fm], bfh[fn], acc[fm][fn], 0, 0, 0);
        }
    }
    __syncthreads();
  }

  // epilogue: C/D layout (m101): col=lane&31, row=(e&3)+8*(e>>2)+4*(lane>>5)
#pragma unroll
  for (int fm = 0; fm < FM; ++fm)
#pragma unroll
    for (int fn = 0; fn < FN; ++fn) {
      const int col = n0 + wn * FN * 32 + fn * 32 + (l & 31);
      const int rbase = m0 + wm * FM * 32 + fm * 32 + 4 * (l >> 5);
#pragma unroll
      for (int e = 0; e < 16; ++e) {
        const int row = rbase + (e & 3) + 8 * (e >> 2);
        float v = acc[fm][fn][e];
        if (EPI == 2) v += E[(size_t)row * lde + col];
        C[(size_t)row * ldc + col] = v;
      }
    }
}

// ---------------- fp32 128x128x16 tiled GEMM (x_proj / dt_proj) ----------------
template <int EPI, bool NCHECK>
__global__ __launch_bounds__(256)
void gemm_k(const float* __restrict__ A, int lda,
            const float* __restrict__ B, int ldb,
            float* __restrict__ C, int ldc,
            int M, int N, int K, size_t czoff,
            const float* __restrict__ E, int lde) {
  __shared__ float As[16][132];
  __shared__ float Bs[16][132];
  const int tid = threadIdx.x;
  const int tx = tid & 15, ty = tid >> 4;
  const int m0 = blockIdx.y * 128;
  const int n0 = blockIdx.x * 128;
  const int kbase = blockIdx.z * K;
  C += (size_t)blockIdx.z * czoff;

  float acc[8][8];
#pragma unroll
  for (int i = 0; i < 8; ++i)
#pragma unroll
    for (int j = 0; j < 8; ++j) acc[i][j] = 0.f;

  const float* Ap = A + (size_t)m0 * lda + kbase;
  const float* Bp = B + (size_t)kbase * ldb + n0;

  const int ar0 = (tid + 0) >> 2,   akq0 = ((tid + 0) & 3) << 2;
  const int ar1 = (tid + 256) >> 2, akq1 = ((tid + 256) & 3) << 2;
  const int bkr0 = (tid + 0) >> 5,   bc0 = ((tid + 0) & 31) << 2;
  const int bkr1 = (tid + 256) >> 5, bc1 = ((tid + 256) & 31) << 2;
  const bool bok0 = !NCHECK || (n0 + bc0) < N;
  const bool bok1 = !NCHECK || (n0 + bc1) < N;

  float4 aR0, aR1, bR0, bR1;
  aR0 = *(const float4*)(Ap + (size_t)ar0 * lda + akq0);
  aR1 = *(const float4*)(Ap + (size_t)ar1 * lda + akq1);
  bR0 = bok0 ? *(const float4*)(Bp + (size_t)bkr0 * ldb + bc0)
             : make_float4(0.f, 0.f, 0.f, 0.f);
  bR1 = bok1 ? *(const float4*)(Bp + (size_t)bkr1 * ldb + bc1)
             : make_float4(0.f, 0.f, 0.f, 0.f);

  for (int kt = 0; kt < K; kt += 16) {
    As[akq0 + 0][ar0] = aR0.x; As[akq0 + 1][ar0] = aR0.y;
    As[akq0 + 2][ar0] = aR0.z; As[akq0 + 3][ar0] = aR0.w;
    As[akq1 + 0][ar1] = aR1.x; As[akq1 + 1][ar1] = aR1.y;
    As[akq1 + 2][ar1] = aR1.z; As[akq1 + 3][ar1] = aR1.w;
    *(float4*)&Bs[bkr0][bc0] = bR0;
    *(float4*)&Bs[bkr1][bc1] = bR1;
    __syncthreads();
    if (kt + 16 < K) {
      const int kn = kt + 16;
      aR0 = *(const float4*)(Ap + (size_t)ar0 * lda + kn + akq0);
      aR1 = *(const float4*)(Ap + (size_t)ar1 * lda + kn + akq1);
      if (bok0) bR0 = *(const float4*)(Bp + (size_t)(kn + bkr0) * ldb + bc0);
      if (bok1) bR1 = *(const float4*)(Bp + (size_t)(kn + bkr1) * ldb + bc1);
    }
#pragma unroll
    for (int kk = 0; kk < 16; ++kk) {
      float a[8], b[8];
      {
        const float4 t0 = *(const float4*)&As[kk][ty << 2];
        const float4 t1 = *(const float4*)&As[kk][64 + (ty << 2)];
        a[0] = t0.x; a[1] = t0.y; a[2] = t0.z; a[3] = t0.w;
        a[4] = t1.x; a[5] = t1.y; a[6] = t1.z; a[7] = t1.w;
        const float4 u0 = *(const float4*)&Bs[kk][tx << 2];
        const float4 u1 = *(const float4*)&Bs[kk][64 + (tx << 2)];
        b[0] = u0.x; b[1] = u0.y; b[2] = u0.z; b[3] = u0.w;
        b[4] = u1.x; b[5] = u1.y; b[6] = u1.z; b[7] = u1.w;
      }
#pragma unroll
      for (int i = 0; i < 8; ++i)
#pragma unroll
        for (int j = 0; j < 8; ++j) acc[i][j] = fmaf(a[i], b[j], acc[i][j]);
    }
    __syncthreads();
  }

#pragma unroll
  for (int i = 0; i < 8; ++i) {
    const int m = m0 + ((i >> 2) << 6) + (ty << 2) + (i & 3);
#pragma unroll
    for (int jh = 0; jh < 2; ++jh) {
      const int n = n0 + (jh << 6) + (tx << 2);
      if (NCHECK && n >= N) continue;
      float4 v;
      v.x = acc[i][jh * 4 + 0];
      v.y = acc[i][jh * 4 + 1];
      v.z = acc[i][jh * 4 + 2];
      v.w = acc[i][jh * 4 + 3];
      if (EPI == 1) {
        v.x = softplus_(v.x + E[n + 0]);
        v.y = softplus_(v.y + E[n + 1]);
        v.z = softplus_(v.z + E[n + 2]);
        v.w = softplus_(v.w + E[n + 3]);
      }
      *(float4*)(C + (size_t)m * ldc + n) = v;
    }
  }
}

// ---------------- causal depthwise conv1d + bias + silu ----------------
__global__ __launch_bounds__(256) void conv_silu_k(const float* __restrict__ xz,
                                                   const float* __restrict__ cw,
                                                   const float* __restrict__ cb,
                                                   float* __restrict__ xc) {
  const int idx = blockIdx.x * 256 + threadIdx.x;
  const int d = idx & (DINNER - 1);
  const int bt = idx >> 11;
  const int t = bt & (L_SEQ - 1);
  const int b = bt >> 11;
  const float4 w4 = ((const float4*)cw)[d];
  const float wj[4] = {w4.x, w4.y, w4.z, w4.w};
  float acc = cb[d];
  const float* base = xz + ((size_t)b * L_SEQ) * 4096 + d;
#pragma unroll
  for (int j = 0; j < 4; ++j) {
    const int tt = t - 3 + j;
    if (tt >= 0) acc = fmaf(wj[j], base[(size_t)tt * 4096], acc);
  }
  xc[(size_t)bt * DINNER + d] = acc * (1.f / (1.f + __expf(-acc)));
}

// ---------------- reduce 8 split-K slices of xp ----------------
__global__ __launch_bounds__(256) void reduce8_k(const float* __restrict__ part,
                                                 float* __restrict__ out, int n) {
  const int i = blockIdx.x * 256 + threadIdx.x;
  if (i < n) {
    float s = 0.f;
#pragma unroll
    for (int j = 0; j < 8; ++j) s += part[(size_t)j * n + i];
    out[i] = s;
  }
}

// ======================= chunked 2-pass selective scan ======================
__global__ __launch_bounds__(256) void scan_p1(const float* __restrict__ delta,
                                               const float* __restrict__ xc,
                                               const float* __restrict__ xp,
                                               const float* __restrict__ logA,
                                               float* __restrict__ hend,
                                               float* __restrict__ sumdv) {
  const int w = blockIdx.x * 4 + (threadIdx.x >> 6);
  const int lane = threadIdx.x & 63;
  const int dg = w & 31, c = (w >> 5) & 31, b = w >> 10;
  const int d = dg * 64 + lane;

  float A_[16];
#pragma unroll
  for (int s = 0; s < 16; ++s) A_[s] = -__expf(logA[d * 16 + s]);
  float h[16];
#pragma unroll
  for (int s = 0; s < 16; ++s) h[s] = 0.f;
  float sdv = 0.f;

  const int row0 = b * L_SEQ + c * CL;
  const float* dp = delta + (size_t)row0 * DINNER + d;
  const float* xq = xc + (size_t)row0 * DINNER + d;
  const float* bp = xp + (size_t)row0 * 96 + DTRANK;

  float dv_n = *dp, xv_n = *xq;
  float4 B0 = *(const float4*)(bp + 0), B1 = *(const float4*)(bp + 4);
  float4 B2 = *(const float4*)(bp + 8), B3 = *(const float4*)(bp + 12);

  for (int t = 0; t < CL; ++t) {
    const float dv = dv_n, xv = xv_n;
    const float Bs[16] = {B0.x, B0.y, B0.z, B0.w, B1.x, B1.y, B1.z, B1.w,
                          B2.x, B2.y, B2.z, B2.w, B3.x, B3.y, B3.z, B3.w};
    if (t + 1 < CL) {
      dp += DINNER; xq += DINNER; bp += 96;
      dv_n = *dp; xv_n = *xq;
      B0 = *(const float4*)(bp + 0); B1 = *(const float4*)(bp + 4);
      B2 = *(const float4*)(bp + 8); B3 = *(const float4*)(bp + 12);
    }
    const float dxv = dv * xv;
    sdv += dv;
#pragma unroll
    for (int s = 0; s < 16; ++s) {
      const float dA = __expf(dv * A_[s]);
      h[s] = fmaf(dA, h[s], dxv * Bs[s]);
    }
  }
  const size_t bc = (size_t)(b * NC + c);
#pragma unroll
  for (int s = 0; s < 16; ++s) hend[(bc * 16 + s) * DINNER + d] = h[s];
  sumdv[bc * DINNER + d] = sdv;
}

__global__ __launch_bounds__(256) void scan_mid(const float* __restrict__ hend,
                                                const float* __restrict__ sumdv,
                                                const float* __restrict__ logA,
                                                float* __restrict__ hin) {
  const int tid = blockIdx.x * 256 + threadIdx.x;
  const int d = tid & (DINNER - 1);
  const int s = (tid >> 11) & 15;
  const int b = tid >> 15;
  const float A = -__expf(logA[d * 16 + s]);
  float hr = 0.f;
  for (int c = 0; c < NC; ++c) {
    const size_t bc = (size_t)(b * NC + c);
    const size_t o = (bc * 16 + s) * DINNER + d;
    hin[o] = hr;
    const float P = __expf(A * sumdv[bc * DINNER + d]);
    hr = fmaf(P, hr, hend[o]);
  }
}

// pass 2: emits y*silu(z) as bf16 hi/lo packed into xz's dead x_ssm columns:
// per 16KB fp32 row of xz: bytes [0,4096) = y_hi u16[2048], [4096,8192) = y_lo,
// z stays at bytes [8192,16384). yout = (u16*)xz, row stride 8192 u16.
__global__ __launch_bounds__(256) void scan_p2(const float* __restrict__ delta,
                                               const float* __restrict__ xc,
                                               const float* __restrict__ xp,
                                               const float* __restrict__ logA,
                                               const float* __restrict__ Dp,
                                               const float* __restrict__ hin,
                                               const float* __restrict__ zin,
                                               u16* __restrict__ yout) {
  const int w = blockIdx.x * 4 + (threadIdx.x >> 6);
  const int lane = threadIdx.x & 63;
  const int dg = w & 31, c = (w >> 5) & 31, b = w >> 10;
  const int d = dg * 64 + lane;

  float A_[16];
#pragma unroll
  for (int s = 0; s < 16; ++s) A_[s] = -__expf(logA[d * 16 + s]);
  const size_t bc = (size_t)(b * NC + c);
  float h[16];
#pragma unroll
  for (int s = 0; s < 16; ++s) h[s] = hin[(bc * 16 + s) * DINNER + d];
  const float Dv = Dp[d];

  const int row0 = b * L_SEQ + c * CL;
  const float* dp = delta + (size_t)row0 * DINNER + d;
  const float* xq = xc + (size_t)row0 * DINNER + d;
  const float* bp = xp + (size_t)row0 * 96 + DTRANK;
  const float* zp = zin + (size_t)row0 * 4096 + d;
  u16* yo = yout + (size_t)row0 * 8192 + d;

  float dv_n = *dp, xv_n = *xq, zv_n = *zp;
  float4 B0 = *(const float4*)(bp + 0), B1 = *(const float4*)(bp + 4);
  float4 B2 = *(const float4*)(bp + 8), B3 = *(const float4*)(bp + 12);
  float4 C0 = *(const float4*)(bp + 16), C1 = *(const float4*)(bp + 20);
  float4 C2 = *(const float4*)(bp + 24), C3 = *(const float4*)(bp + 28);

  for (int t = 0; t < CL; ++t) {
    const float dv = dv_n, xv = xv_n, zv = zv_n;
    const float Bs[16] = {B0.x, B0.y, B0.z, B0.w, B1.x, B1.y, B1.z, B1.w,
                          B2.x, B2.y, B2.z, B2.w, B3.x, B3.y, B3.z, B3.w};
    const float Cs[16] = {C0.x, C0.y, C0.z, C0.w, C1.x, C1.y, C1.z, C1.w,
                          C2.x, C2.y, C2.z, C2.w, C3.x, C3.y, C3.z, C3.w};
    if (t + 1 < CL) {
      dp += DINNER; xq += DINNER; bp += 96; zp += 4096;
      dv_n = *dp; xv_n = *xq; zv_n = *zp;
      B0 = *(const float4*)(bp + 0); B1 = *(const float4*)(bp + 4);
      B2 = *(const float4*)(bp + 8); B3 = *(const float4*)(bp + 12);
      C0 = *(const float4*)(bp + 16); C1 = *(const float4*)(bp + 20);
      C2 = *(const float4*)(bp + 24); C3 = *(const float4*)(bp + 28);
    }
    const float dxv = dv * xv;
    float y = xv * Dv;
#pragma unroll
    for (int s = 0; s < 16; ++s) {
      const float dA = __expf(dv * A_[s]);
      h[s] = fmaf(dA, h[s], dxv * Bs[s]);
      y = fmaf(h[s], Cs[s], y);
    }
    const float g = zv / (1.f + __expf(-zv));
    u16 yh, yl;
    bsplit(y * g, yh, yl);
    yo[0] = yh;
    yo[2048] = yl;
    yo += 8192;
  }
}

// ---------------------------------------------------------------------------
extern "C" void kernel_launch(void* const* d_in, const int* in_sizes, int n_in,
                              void* d_out, int out_size, void* d_ws, size_t ws_size,
                              hipStream_t stream) {
  const float* x = (const float*)d_in[0];
  const float* norm_w = (const float*)d_in[1];
  const float* in_w = (const float*)d_in[2];
  const float* conv_w = (const float*)d_in[3];
  const float* conv_b = (const float*)d_in[4];
  const float* xproj_w = (const float*)d_in[5];
  const float* dt_w = (const float*)d_in[6];
  const float* dt_b = (const float*)d_in[7];
  const float* log_A = (const float*)d_in[8];
  const float* D_param = (const float*)d_in[9];
  const float* out_w = (const float*)d_in[10];
  float* out = (float*)d_out;

  float* ws = (float*)d_ws;
  float* xn = ws;                                  // region A: 4M floats
  float* xz = xn + (size_t)BLROWS * DMODEL;        // 16M floats
  float* xc = xz + (size_t)BLROWS * 4096;          // region B: 8M floats
  float* xp_p = xc + (size_t)BLROWS * DINNER;      // region C: 3.15M floats
  float* xp = xp_p + (size_t)8 * BLROWS * 96;      // 0.39M floats
  float* delta = xp + (size_t)BLROWS * 96;         // 8M floats
  const size_t need = ((size_t)(delta - ws) + (size_t)BLROWS * DINNER) * 4;
  if (ws_size < need) return;

  // region A: xn hi/lo bf16 (live until in_proj), then scan hend
  u16* xnh = (u16*)xn;                             // 4M u16
  u16* xnl = xnh + (size_t)BLROWS * DMODEL;        // 4M u16 (= 16MB total, fits)
  float* hend = xn;                                // scan phase (xn* dead)
  // region B: in_w^T hi/lo (live until in_proj; conv overwrites after)
  u16* inwh = (u16*)xc;                            // 4M u16
  u16* inwl = inwh + (size_t)DMODEL * 4096;        // 4M u16 (16MB of 32MB)
  // region C: x_proj partials -> scan hin/sumdv -> out_w^T hi/lo
  float* hin = xp_p;
  float* sumdv = xp_p + (size_t)2 * NC * 16 * DINNER;
  u16* owh = (u16*)xp_p;                           // 2M u16 (after scan_p2)
  u16* owl = owh + (size_t)DINNER * DMODEL;        // 2M u16 (8MB of 12.6MB)
  // y (scan output) packed as bf16 hi/lo inside xz rows (see scan_p2)
  u16* yh = (u16*)xz;
  u16* yl = yh + 2048;

  // 1. transpose+split in_w [1024][4096] -> [4096][1024] bf16 hi/lo
  tsplit_k<<<dim3(4096 / 32, DMODEL / 32), 256, 0, stream>>>(in_w, DMODEL, 4096,
                                                             inwh, inwl);
  // 2. RMSNorm + split -> xn_hi/lo
  rmsnorm_split_k<<<BLROWS, 256, 0, stream>>>(x, norm_w, xnh, xnl);
  // 3. in_proj: MFMA split-bf16, BM=BN=128, grid 32x32
  mgemm_k<2, 2, 2, 2, 0><<<dim3(32, 32), 256, 0, stream>>>(
      xnh, xnl, DMODEL, inwh, inwl, DMODEL, xz, 4096, nullptr, 0, DMODEL);
  // 4. conv + silu (reads xz cols [0,2048) fp32)
  conv_silu_k<<<(BLROWS * DINNER) / 256, 256, 0, stream>>>(xz, conv_w, conv_b, xc);
  // 5. x_proj split-K=8 (fp32)
  gemm_k<0, true><<<dim3(1, 32, 8), 256, 0, stream>>>(
      xc, DINNER, xproj_w, 96, xp_p, 96, BLROWS, 96, DINNER / 8,
      (size_t)BLROWS * 96, nullptr, 0);
  reduce8_k<<<(BLROWS * 96) / 256, 256, 0, stream>>>(xp_p, xp, BLROWS * 96);
  // 6. dt_proj + softplus (fp32)
  gemm_k<1, false><<<dim3(16, 32, 1), 256, 0, stream>>>(
      xp, 96, dt_w, DINNER, delta, DINNER, BLROWS, DINNER, DTRANK, 0, dt_b, 0);
  // 7. chunked scan; p2 writes bf16-split y into xz (z cols untouched)
  scan_p1<<<512, 256, 0, stream>>>(delta, xc, xp, log_A, hend, sumdv);
  scan_mid<<<256, 256, 0, stream>>>(hend, sumdv, log_A, hin);
  scan_p2<<<512, 256, 0, stream>>>(delta, xc, xp, log_A, D_param, hin,
                                   xz + DINNER, yh);
  // 8. transpose+split out_w [2048][1024] -> [1024][2048] (xp_p region now dead)
  tsplit_k<<<dim3(DMODEL / 32, DINNER / 32), 256, 0, stream>>>(out_w, DINNER,
                                                               DMODEL, owh, owl);
  // 9. out_proj: MFMA split-bf16, BM=64 BN=128, grid 8x64, residual fused
  mgemm_k<2, 2, 1, 2, 2><<<dim3(8, 64), 256, 0, stream>>>(
      yh, yl, 8192, owh, owl, DINNER, out, DMODEL, x, DMODEL, DINNER);
}

// Round 12
// 470.751 us; speedup vs baseline: 2.8063x; 1.0156x over previous
//
#include <hip/hip_runtime.h>
#include <hip/hip_bf16.h>
#include <math.h>

// ---------------------------------------------------------------------------
// QwenMambaLayer for MI355X.
// rmsnorm(+bf16 split) -> MFMA split-bf16 gemm(in_proj) -> conv1d+silu (vec4)
//   -> fp32 gemm(x_proj split-K) -> reduce -> fp32 gemm(dt_proj)+softplus
//   -> chunked 2-pass scan (p2 emits bf16-split y) -> MFMA split-bf16
//   gemm(out_proj)+residual.
// Pending vs round-7 measured baseline (478us):
//  (a) line/slot XOR swizzle in mgemm: fixes 8-way LDS bank conflict
//      (SQ_LDS_BANK_CONFLICT 2.5e7 @ in_proj, 126us, MfmaUtil 36%).
//  (b) conv_silu vectorized 4d/thread (float4 IO, identical per-channel math).
// ---------------------------------------------------------------------------

#define L_SEQ   2048
#define NB      2
#define DMODEL  1024
#define DINNER  2048
#define DSTATE  16
#define DTRANK  64
#define BLROWS  (NB * L_SEQ)   // 4096
#define NC      32             // L-chunks for the scan
#define CL      (L_SEQ / NC)   // 64 rows per chunk

typedef unsigned short u16;
typedef __attribute__((ext_vector_type(8))) short short8v;   // 8 bf16 = 4 VGPR
typedef __attribute__((ext_vector_type(16))) float f32x16;

__device__ __forceinline__ float softplus_(float x) {
  return fmaxf(x, 0.f) + log1pf(expf(-fabsf(x)));
}
__device__ __forceinline__ void bsplit(float v, u16& h, u16& l) {
  __hip_bfloat16 bh = __float2bfloat16(v);
  float fh = __bfloat162float(bh);
  __hip_bfloat16 bl = __float2bfloat16(v - fh);
  h = *(u16*)&bh; l = *(u16*)&bl;
}
// LDS swizzle (u16 offset) for [rows][4 slots of 8 u16] tiles.
// line = r>>1 (128B bank-line), slot = (r&1)*4+s, phys = slot ^ (line&7):
// fragment reads (32 rows, fixed s) spread 4 lanes per 16B bank-group (floor);
// staged writes (lane l: slot=l&7, line=l>>3) cover all 8 groups per line.
__device__ __forceinline__ int swz(int r, int s) {
  const int line = r >> 1;
  const int slot = ((r & 1) << 2) | s;
  return line * 64 + ((slot ^ (line & 7)) << 3);
}

// ---------------- RMSNorm + bf16 hi/lo split ----------------
__global__ __launch_bounds__(256) void rmsnorm_split_k(const float* __restrict__ x,
                                                       const float* __restrict__ w,
                                                       u16* __restrict__ xnh,
                                                       u16* __restrict__ xnl) {
  const int row = blockIdx.x;
  const float4* xr = (const float4*)(x + (size_t)row * DMODEL);
  float4 v = xr[threadIdx.x];
  float ss = v.x * v.x + v.y * v.y + v.z * v.z + v.w * v.w;
#pragma unroll
  for (int o = 32; o > 0; o >>= 1) ss += __shfl_down(ss, o);
  __shared__ float sred[4];
  const int lane = threadIdx.x & 63, wv = threadIdx.x >> 6;
  if (lane == 0) sred[wv] = ss;
  __syncthreads();
  const float tot = sred[0] + sred[1] + sred[2] + sred[3];
  const float rinv = rsqrtf(tot * (1.f / DMODEL) + 1e-6f);
  const float4 wv4 = ((const float4*)w)[threadIdx.x];
  float o[4] = {v.x * rinv * wv4.x, v.y * rinv * wv4.y,
                v.z * rinv * wv4.z, v.w * rinv * wv4.w};
  u16 h[4], lo[4];
#pragma unroll
  for (int i = 0; i < 4; ++i) bsplit(o[i], h[i], lo[i]);
  uint2 ph, pl;
  ph.x = (unsigned)h[0] | ((unsigned)h[1] << 16);
  ph.y = (unsigned)h[2] | ((unsigned)h[3] << 16);
  pl.x = (unsigned)lo[0] | ((unsigned)lo[1] << 16);
  pl.y = (unsigned)lo[2] | ((unsigned)lo[3] << 16);
  *(uint2*)(xnh + (size_t)row * DMODEL + threadIdx.x * 4) = ph;
  *(uint2*)(xnl + (size_t)row * DMODEL + threadIdx.x * 4) = pl;
}

// ---------------- transpose + bf16 split: src[R][C] -> dst[C][R] ----------------
__global__ __launch_bounds__(256) void tsplit_k(const float* __restrict__ src,
                                                int R, int C,
                                                u16* __restrict__ dh,
                                                u16* __restrict__ dl) {
  __shared__ float tile[32][33];
  const int tx = threadIdx.x & 31, ty = threadIdx.x >> 5;
  const int r0 = blockIdx.y * 32, c0 = blockIdx.x * 32;
#pragma unroll
  for (int i = 0; i < 4; ++i)
    tile[ty + i * 8][tx] = src[(size_t)(r0 + ty + i * 8) * C + c0 + tx];
  __syncthreads();
#pragma unroll
  for (int i = 0; i < 4; ++i) {
    const float v = tile[tx][ty + i * 8];
    u16 h, l; bsplit(v, h, l);
    const size_t o = (size_t)(c0 + ty + i * 8) * R + r0 + tx;
    dh[o] = h; dl[o] = l;
  }
}

// ---------------- split-bf16 MFMA GEMM ----------------
// C[M,N] (+E residual if EPI==2) = (Ah+Al)[M,K] @ (Bh+Bl)[K,N], 3-term split.
// A stored [M][K] bf16 row-major (lda); B PRE-TRANSPOSED [N][K] bf16 (ldb).
// Block tile BM x BN, BK=32; wave grid GM x GN, FM x FN 32x32 frags per wave.
template <int GM, int GN, int FM, int FN, int EPI>
__global__ __launch_bounds__(GM * GN * 64)
void mgemm_k(const u16* __restrict__ Ah, const u16* __restrict__ Al, int lda,
             const u16* __restrict__ Bh, const u16* __restrict__ Bl, int ldb,
             float* __restrict__ C, int ldc,
             const float* __restrict__ E, int lde, int K) {
  constexpr int BM = GM * FM * 32, BN = GN * FN * 32, T = GM * GN * 64;
  constexpr int AV = (BM * 4) / T, BV = (BN * 4) / T;
  static_assert((BM * 4) % T == 0 && (BN * 4) % T == 0, "staging divisibility");
  __shared__ __align__(16) u16 smem[(BM + BN) * 64];
  u16* sAh = smem;
  u16* sAl = smem + BM * 32;
  u16* sBh = smem + BM * 64;
  u16* sBl = smem + BM * 64 + BN * 32;

  const int tid = threadIdx.x;
  const int l = tid & 63;
  const int wv = tid >> 6;
  const int wm = wv / GN, wn = wv % GN;
  const int m0 = blockIdx.y * BM, n0 = blockIdx.x * BN;

  f32x16 acc[FM][FN];
#pragma unroll
  for (int i = 0; i < FM; ++i)
#pragma unroll
    for (int j = 0; j < FN; ++j)
#pragma unroll
      for (int e = 0; e < 16; ++e) acc[i][j][e] = 0.f;

  short8v pah[AV], pal[AV], pbh[BV], pbl[BV];
#pragma unroll
  for (int u = 0; u < AV; ++u) {
    const int li = tid + u * T, r = li >> 2, ks = li & 3;
    pah[u] = *(const short8v*)(Ah + (size_t)(m0 + r) * lda + ks * 8);
    pal[u] = *(const short8v*)(Al + (size_t)(m0 + r) * lda + ks * 8);
  }
#pragma unroll
  for (int u = 0; u < BV; ++u) {
    const int li = tid + u * T, r = li >> 2, ks = li & 3;
    pbh[u] = *(const short8v*)(Bh + (size_t)(n0 + r) * ldb + ks * 8);
    pbl[u] = *(const short8v*)(Bl + (size_t)(n0 + r) * ldb + ks * 8);
  }

  const int nk = K >> 5;
  for (int kt = 0; kt < nk; ++kt) {
#pragma unroll
    for (int u = 0; u < AV; ++u) {
      const int li = tid + u * T, r = li >> 2, ks = li & 3;
      const int off = swz(r, ks);
      *(short8v*)(sAh + off) = pah[u];
      *(short8v*)(sAl + off) = pal[u];
    }
#pragma unroll
    for (int u = 0; u < BV; ++u) {
      const int li = tid + u * T, r = li >> 2, ks = li & 3;
      const int off = swz(r, ks);
      *(short8v*)(sBh + off) = pbh[u];
      *(short8v*)(sBl + off) = pbl[u];
    }
    __syncthreads();
    if (kt + 1 < nk) {  // reg prefetch of next K-tile (hides global latency)
      const int ko = (kt + 1) * 32;
#pragma unroll
      for (int u = 0; u < AV; ++u) {
        const int li = tid + u * T, r = li >> 2, ks = li & 3;
        pah[u] = *(const short8v*)(Ah + (size_t)(m0 + r) * lda + ko + ks * 8);
        pal[u] = *(const short8v*)(Al + (size_t)(m0 + r) * lda + ko + ks * 8);
      }
#pragma unroll
      for (int u = 0; u < BV; ++u) {
        const int li = tid + u * T, r = li >> 2, ks = li & 3;
        pbh[u] = *(const short8v*)(Bh + (size_t)(n0 + r) * ldb + ko + ks * 8);
        pbl[u] = *(const short8v*)(Bl + (size_t)(n0 + r) * ldb + ko + ks * 8);
      }
    }
#pragma unroll
    for (int ks2 = 0; ks2 < 2; ++ks2) {
      const int kslot = ks2 * 2 + (l >> 5);
      short8v afh[FM], afl[FM], bfh[FN], bfl[FN];
#pragma unroll
      for (int fm = 0; fm < FM; ++fm) {
        const int r = wm * FM * 32 + fm * 32 + (l & 31);
        const int off = swz(r, kslot);
        afh[fm] = *(const short8v*)(sAh + off);
        afl[fm] = *(const short8v*)(sAl + off);
      }
#pragma unroll
      for (int fn = 0; fn < FN; ++fn) {
        const int r = wn * FN * 32 + fn * 32 + (l & 31);
        const int off = swz(r, kslot);
        bfh[fn] = *(const short8v*)(sBh + off);
        bfl[fn] = *(const short8v*)(sBl + off);
      }
#pragma unroll
      for (int fm = 0; fm < FM; ++fm)
#pragma unroll
        for (int fn = 0; fn < FN; ++fn) {
          acc[fm][fn] = __builtin_amdgcn_mfma_f32_32x32x16_bf16(
              afh[fm], bfh[fn], acc[fm][fn], 0, 0, 0);
          acc[fm][fn] = __builtin_amdgcn_mfma_f32_32x32x16_bf16(
              afh[fm], bfl[fn], acc[fm][fn], 0, 0, 0);
          acc[fm][fn] = __builtin_amdgcn_mfma_f32_32x32x16_bf16(
              afl[fm], bfh[fn], acc[fm][fn], 0, 0, 0);
        }
    }
    __syncthreads();
  }

  // epilogue: C/D layout (m101): col=lane&31, row=(e&3)+8*(e>>2)+4*(lane>>5)
#pragma unroll
  for (int fm = 0; fm < FM; ++fm)
#pragma unroll
    for (int fn = 0; fn < FN; ++fn) {
      const int col = n0 + wn * FN * 32 + fn * 32 + (l & 31);
      const int rbase = m0 + wm * FM * 32 + fm * 32 + 4 * (l >> 5);
#pragma unroll
      for (int e = 0; e < 16; ++e) {
        const int row = rbase + (e & 3) + 8 * (e >> 2);
        float v = acc[fm][fn][e];
        if (EPI == 2) v += E[(size_t)row * lde + col];
        C[(size_t)row * ldc + col] = v;
      }
    }
}

// ---------------- fp32 128x128x16 tiled GEMM (x_proj / dt_proj) ----------------
template <int EPI, bool NCHECK>
__global__ __launch_bounds__(256)
void gemm_k(const float* __restrict__ A, int lda,
            const float* __restrict__ B, int ldb,
            float* __restrict__ C, int ldc,
            int M, int N, int K, size_t czoff,
            const float* __restrict__ E, int lde) {
  __shared__ float As[16][132];
  __shared__ float Bs[16][132];
  const int tid = threadIdx.x;
  const int tx = tid & 15, ty = tid >> 4;
  const int m0 = blockIdx.y * 128;
  const int n0 = blockIdx.x * 128;
  const int kbase = blockIdx.z * K;
  C += (size_t)blockIdx.z * czoff;

  float acc[8][8];
#pragma unroll
  for (int i = 0; i < 8; ++i)
#pragma unroll
    for (int j = 0; j < 8; ++j) acc[i][j] = 0.f;

  const float* Ap = A + (size_t)m0 * lda + kbase;
  const float* Bp = B + (size_t)kbase * ldb + n0;

  const int ar0 = (tid + 0) >> 2,   akq0 = ((tid + 0) & 3) << 2;
  const int ar1 = (tid + 256) >> 2, akq1 = ((tid + 256) & 3) << 2;
  const int bkr0 = (tid + 0) >> 5,   bc0 = ((tid + 0) & 31) << 2;
  const int bkr1 = (tid + 256) >> 5, bc1 = ((tid + 256) & 31) << 2;
  const bool bok0 = !NCHECK || (n0 + bc0) < N;
  const bool bok1 = !NCHECK || (n0 + bc1) < N;

  float4 aR0, aR1, bR0, bR1;
  aR0 = *(const float4*)(Ap + (size_t)ar0 * lda + akq0);
  aR1 = *(const float4*)(Ap + (size_t)ar1 * lda + akq1);
  bR0 = bok0 ? *(const float4*)(Bp + (size_t)bkr0 * ldb + bc0)
             : make_float4(0.f, 0.f, 0.f, 0.f);
  bR1 = bok1 ? *(const float4*)(Bp + (size_t)bkr1 * ldb + bc1)
             : make_float4(0.f, 0.f, 0.f, 0.f);

  for (int kt = 0; kt < K; kt += 16) {
    As[akq0 + 0][ar0] = aR0.x; As[akq0 + 1][ar0] = aR0.y;
    As[akq0 + 2][ar0] = aR0.z; As[akq0 + 3][ar0] = aR0.w;
    As[akq1 + 0][ar1] = aR1.x; As[akq1 + 1][ar1] = aR1.y;
    As[akq1 + 2][ar1] = aR1.z; As[akq1 + 3][ar1] = aR1.w;
    *(float4*)&Bs[bkr0][bc0] = bR0;
    *(float4*)&Bs[bkr1][bc1] = bR1;
    __syncthreads();
    if (kt + 16 < K) {
      const int kn = kt + 16;
      aR0 = *(const float4*)(Ap + (size_t)ar0 * lda + kn + akq0);
      aR1 = *(const float4*)(Ap + (size_t)ar1 * lda + kn + akq1);
      if (bok0) bR0 = *(const float4*)(Bp + (size_t)(kn + bkr0) * ldb + bc0);
      if (bok1) bR1 = *(const float4*)(Bp + (size_t)(kn + bkr1) * ldb + bc1);
    }
#pragma unroll
    for (int kk = 0; kk < 16; ++kk) {
      float a[8], b[8];
      {
        const float4 t0 = *(const float4*)&As[kk][ty << 2];
        const float4 t1 = *(const float4*)&As[kk][64 + (ty << 2)];
        a[0] = t0.x; a[1] = t0.y; a[2] = t0.z; a[3] = t0.w;
        a[4] = t1.x; a[5] = t1.y; a[6] = t1.z; a[7] = t1.w;
        const float4 u0 = *(const float4*)&Bs[kk][tx << 2];
        const float4 u1 = *(const float4*)&Bs[kk][64 + (tx << 2)];
        b[0] = u0.x; b[1] = u0.y; b[2] = u0.z; b[3] = u0.w;
        b[4] = u1.x; b[5] = u1.y; b[6] = u1.z; b[7] = u1.w;
      }
#pragma unroll
      for (int i = 0; i < 8; ++i)
#pragma unroll
        for (int j = 0; j < 8; ++j) acc[i][j] = fmaf(a[i], b[j], acc[i][j]);
    }
    __syncthreads();
  }

#pragma unroll
  for (int i = 0; i < 8; ++i) {
    const int m = m0 + ((i >> 2) << 6) + (ty << 2) + (i & 3);
#pragma unroll
    for (int jh = 0; jh < 2; ++jh) {
      const int n = n0 + (jh << 6) + (tx << 2);
      if (NCHECK && n >= N) continue;
      float4 v;
      v.x = acc[i][jh * 4 + 0];
      v.y = acc[i][jh * 4 + 1];
      v.z = acc[i][jh * 4 + 2];
      v.w = acc[i][jh * 4 + 3];
      if (EPI == 1) {
        v.x = softplus_(v.x + E[n + 0]);
        v.y = softplus_(v.y + E[n + 1]);
        v.z = softplus_(v.z + E[n + 2]);
        v.w = softplus_(v.w + E[n + 3]);
      }
      *(float4*)(C + (size_t)m * ldc + n) = v;
    }
  }
}

// ---------------- causal depthwise conv1d + bias + silu (vec4) ----------------
// 4 consecutive d per thread; float4 loads/stores; same per-channel fmaf order
// as the scalar version (bit-identical output).
__global__ __launch_bounds__(256) void conv_silu_k(const float* __restrict__ xz,
                                                   const float* __restrict__ cw,
                                                   const float* __restrict__ cb,
                                                   float* __restrict__ xc) {
  const int idx = blockIdx.x * 256 + threadIdx.x;  // over 4096*512
  const int d4 = idx & 511;
  const int bt = idx >> 9;
  const int t = bt & (L_SEQ - 1);
  const int b = bt >> 11;
  const int d = d4 << 2;
  const float4 w0 = ((const float4*)cw)[d + 0];  // taps of channel d+0
  const float4 w1 = ((const float4*)cw)[d + 1];
  const float4 w2 = ((const float4*)cw)[d + 2];
  const float4 w3 = ((const float4*)cw)[d + 3];
  float4 acc = ((const float4*)cb)[d4];
  const float* base = xz + ((size_t)b * L_SEQ) * 4096 + d;
#pragma unroll
  for (int j = 0; j < 4; ++j) {
    const int tt = t - 3 + j;
    if (tt >= 0) {
      const float4 v = *(const float4*)(base + (size_t)tt * 4096);
      acc.x = fmaf((&w0.x)[j], v.x, acc.x);
      acc.y = fmaf((&w1.x)[j], v.y, acc.y);
      acc.z = fmaf((&w2.x)[j], v.z, acc.z);
      acc.w = fmaf((&w3.x)[j], v.w, acc.w);
    }
  }
  acc.x *= 1.f / (1.f + __expf(-acc.x));
  acc.y *= 1.f / (1.f + __expf(-acc.y));
  acc.z *= 1.f / (1.f + __expf(-acc.z));
  acc.w *= 1.f / (1.f + __expf(-acc.w));
  ((float4*)xc)[(size_t)bt * 512 + d4] = acc;
}

// ---------------- reduce 8 split-K slices of xp ----------------
__global__ __launch_bounds__(256) void reduce8_k(const float* __restrict__ part,
                                                 float* __restrict__ out, int n) {
  const int i = blockIdx.x * 256 + threadIdx.x;
  if (i < n) {
    float s = 0.f;
#pragma unroll
    for (int j = 0; j < 8; ++j) s += part[(size_t)j * n + i];
    out[i] = s;
  }
}

// ======================= chunked 2-pass selective scan ======================
__global__ __launch_bounds__(256) void scan_p1(const float* __restrict__ delta,
                                               const float* __restrict__ xc,
                                               const float* __restrict__ xp,
                                               const float* __restrict__ logA,
                                               float* __restrict__ hend,
                                               float* __restrict__ sumdv) {
  const int w = blockIdx.x * 4 + (threadIdx.x >> 6);
  const int lane = threadIdx.x & 63;
  const int dg = w & 31, c = (w >> 5) & 31, b = w >> 10;
  const int d = dg * 64 + lane;

  float A_[16];
#pragma unroll
  for (int s = 0; s < 16; ++s) A_[s] = -__expf(logA[d * 16 + s]);
  float h[16];
#pragma unroll
  for (int s = 0; s < 16; ++s) h[s] = 0.f;
  float sdv = 0.f;

  const int row0 = b * L_SEQ + c * CL;
  const float* dp = delta + (size_t)row0 * DINNER + d;
  const float* xq = xc + (size_t)row0 * DINNER + d;
  const float* bp = xp + (size_t)row0 * 96 + DTRANK;

  float dv_n = *dp, xv_n = *xq;
  float4 B0 = *(const float4*)(bp + 0), B1 = *(const float4*)(bp + 4);
  float4 B2 = *(const float4*)(bp + 8), B3 = *(const float4*)(bp + 12);

  for (int t = 0; t < CL; ++t) {
    const float dv = dv_n, xv = xv_n;
    const float Bs[16] = {B0.x, B0.y, B0.z, B0.w, B1.x, B1.y, B1.z, B1.w,
                          B2.x, B2.y, B2.z, B2.w, B3.x, B3.y, B3.z, B3.w};
    if (t + 1 < CL) {
      dp += DINNER; xq += DINNER; bp += 96;
      dv_n = *dp; xv_n = *xq;
      B0 = *(const float4*)(bp + 0); B1 = *(const float4*)(bp + 4);
      B2 = *(const float4*)(bp + 8); B3 = *(const float4*)(bp + 12);
    }
    const float dxv = dv * xv;
    sdv += dv;
#pragma unroll
    for (int s = 0; s < 16; ++s) {
      const float dA = __expf(dv * A_[s]);
      h[s] = fmaf(dA, h[s], dxv * Bs[s]);
    }
  }
  const size_t bc = (size_t)(b * NC + c);
#pragma unroll
  for (int s = 0; s < 16; ++s) hend[(bc * 16 + s) * DINNER + d] = h[s];
  sumdv[bc * DINNER + d] = sdv;
}

__global__ __launch_bounds__(256) void scan_mid(const float* __restrict__ hend,
                                                const float* __restrict__ sumdv,
                                                const float* __restrict__ logA,
                                                float* __restrict__ hin) {
  const int tid = blockIdx.x * 256 + threadIdx.x;
  const int d = tid & (DINNER - 1);
  const int s = (tid >> 11) & 15;
  const int b = tid >> 15;
  const float A = -__expf(logA[d * 16 + s]);
  float hr = 0.f;
  for (int c = 0; c < NC; ++c) {
    const size_t bc = (size_t)(b * NC + c);
    const size_t o = (bc * 16 + s) * DINNER + d;
    hin[o] = hr;
    const float P = __expf(A * sumdv[bc * DINNER + d]);
    hr = fmaf(P, hr, hend[o]);
  }
}

// pass 2: emits y*silu(z) as bf16 hi/lo packed into xz's dead x_ssm columns:
// per 16KB fp32 row of xz: bytes [0,4096) = y_hi u16[2048], [4096,8192) = y_lo,
// z stays at bytes [8192,16384). yout = (u16*)xz, row stride 8192 u16.
__global__ __launch_bounds__(256) void scan_p2(const float* __restrict__ delta,
                                               const float* __restrict__ xc,
                                               const float* __restrict__ xp,
                                               const float* __restrict__ logA,
                                               const float* __restrict__ Dp,
                                               const float* __restrict__ hin,
                                               const float* __restrict__ zin,
                                               u16* __restrict__ yout) {
  const int w = blockIdx.x * 4 + (threadIdx.x >> 6);
  const int lane = threadIdx.x & 63;
  const int dg = w & 31, c = (w >> 5) & 31, b = w >> 10;
  const int d = dg * 64 + lane;

  float A_[16];
#pragma unroll
  for (int s = 0; s < 16; ++s) A_[s] = -__expf(logA[d * 16 + s]);
  const size_t bc = (size_t)(b * NC + c);
  float h[16];
#pragma unroll
  for (int s = 0; s < 16; ++s) h[s] = hin[(bc * 16 + s) * DINNER + d];
  const float Dv = Dp[d];

  const int row0 = b * L_SEQ + c * CL;
  const float* dp = delta + (size_t)row0 * DINNER + d;
  const float* xq = xc + (size_t)row0 * DINNER + d;
  const float* bp = xp + (size_t)row0 * 96 + DTRANK;
  const float* zp = zin + (size_t)row0 * 4096 + d;
  u16* yo = yout + (size_t)row0 * 8192 + d;

  float dv_n = *dp, xv_n = *xq, zv_n = *zp;
  float4 B0 = *(const float4*)(bp + 0), B1 = *(const float4*)(bp + 4);
  float4 B2 = *(const float4*)(bp + 8), B3 = *(const float4*)(bp + 12);
  float4 C0 = *(const float4*)(bp + 16), C1 = *(const float4*)(bp + 20);
  float4 C2 = *(const float4*)(bp + 24), C3 = *(const float4*)(bp + 28);

  for (int t = 0; t < CL; ++t) {
    const float dv = dv_n, xv = xv_n, zv = zv_n;
    const float Bs[16] = {B0.x, B0.y, B0.z, B0.w, B1.x, B1.y, B1.z, B1.w,
                          B2.x, B2.y, B2.z, B2.w, B3.x, B3.y, B3.z, B3.w};
    const float Cs[16] = {C0.x, C0.y, C0.z, C0.w, C1.x, C1.y, C1.z, C1.w,
                          C2.x, C2.y, C2.z, C2.w, C3.x, C3.y, C3.z, C3.w};
    if (t + 1 < CL) {
      dp += DINNER; xq += DINNER; bp += 96; zp += 4096;
      dv_n = *dp; xv_n = *xq; zv_n = *zp;
      B0 = *(const float4*)(bp + 0); B1 = *(const float4*)(bp + 4);
      B2 = *(const float4*)(bp + 8); B3 = *(const float4*)(bp + 12);
      C0 = *(const float4*)(bp + 16); C1 = *(const float4*)(bp + 20);
      C2 = *(const float4*)(bp + 24); C3 = *(const float4*)(bp + 28);
    }
    const float dxv = dv * xv;
    float y = xv * Dv;
#pragma unroll
    for (int s = 0; s < 16; ++s) {
      const float dA = __expf(dv * A_[s]);
      h[s] = fmaf(dA, h[s], dxv * Bs[s]);
      y = fmaf(h[s], Cs[s], y);
    }
    const float g = zv / (1.f + __expf(-zv));
    u16 yh, yl;
    bsplit(y * g, yh, yl);
    yo[0] = yh;
    yo[2048] = yl;
    yo += 8192;
  }
}

// ---------------------------------------------------------------------------
extern "C" void kernel_launch(void* const* d_in, const int* in_sizes, int n_in,
                              void* d_out, int out_size, void* d_ws, size_t ws_size,
                              hipStream_t stream) {
  const float* x = (const float*)d_in[0];
  const float* norm_w = (const float*)d_in[1];
  const float* in_w = (const float*)d_in[2];
  const float* conv_w = (const float*)d_in[3];
  const float* conv_b = (const float*)d_in[4];
  const float* xproj_w = (const float*)d_in[5];
  const float* dt_w = (const float*)d_in[6];
  const float* dt_b = (const float*)d_in[7];
  const float* log_A = (const float*)d_in[8];
  const float* D_param = (const float*)d_in[9];
  const float* out_w = (const float*)d_in[10];
  float* out = (float*)d_out;

  float* ws = (float*)d_ws;
  float* xn = ws;                                  // region A: 4M floats
  float* xz = xn + (size_t)BLROWS * DMODEL;        // 16M floats
  float* xc = xz + (size_t)BLROWS * 4096;          // region B: 8M floats
  float* xp_p = xc + (size_t)BLROWS * DINNER;      // region C: 3.15M floats
  float* xp = xp_p + (size_t)8 * BLROWS * 96;      // 0.39M floats
  float* delta = xp + (size_t)BLROWS * 96;         // 8M floats
  const size_t need = ((size_t)(delta - ws) + (size_t)BLROWS * DINNER) * 4;
  if (ws_size < need) return;

  // region A: xn hi/lo bf16 (live until in_proj), then scan hend
  u16* xnh = (u16*)xn;                             // 4M u16
  u16* xnl = xnh + (size_t)BLROWS * DMODEL;        // 4M u16 (= 16MB total, fits)
  float* hend = xn;                                // scan phase (xn* dead)
  // region B: in_w^T hi/lo (live until in_proj; conv overwrites after)
  u16* inwh = (u16*)xc;                            // 4M u16
  u16* inwl = inwh + (size_t)DMODEL * 4096;        // 4M u16 (16MB of 32MB)
  // region C: x_proj partials -> scan hin/sumdv -> out_w^T hi/lo
  float* hin = xp_p;
  float* sumdv = xp_p + (size_t)2 * NC * 16 * DINNER;
  u16* owh = (u16*)xp_p;                           // 2M u16 (after scan_p2)
  u16* owl = owh + (size_t)DINNER * DMODEL;        // 2M u16 (8MB of 12.6MB)
  // y (scan output) packed as bf16 hi/lo inside xz rows (see scan_p2)
  u16* yh = (u16*)xz;
  u16* yl = yh + 2048;

  // 1. transpose+split in_w [1024][4096] -> [4096][1024] bf16 hi/lo
  tsplit_k<<<dim3(4096 / 32, DMODEL / 32), 256, 0, stream>>>(in_w, DMODEL, 4096,
                                                             inwh, inwl);
  // 2. RMSNorm + split -> xn_hi/lo
  rmsnorm_split_k<<<BLROWS, 256, 0, stream>>>(x, norm_w, xnh, xnl);
  // 3. in_proj: MFMA split-bf16, BM=BN=128, grid 32x32
  mgemm_k<2, 2, 2, 2, 0><<<dim3(32, 32), 256, 0, stream>>>(
      xnh, xnl, DMODEL, inwh, inwl, DMODEL, xz, 4096, nullptr, 0, DMODEL);
  // 4. conv + silu (vec4; reads xz cols [0,2048) fp32)
  conv_silu_k<<<(BLROWS * DINNER) / 1024, 256, 0, stream>>>(xz, conv_w, conv_b, xc);
  // 5. x_proj split-K=8 (fp32)
  gemm_k<0, true><<<dim3(1, 32, 8), 256, 0, stream>>>(
      xc, DINNER, xproj_w, 96, xp_p, 96, BLROWS, 96, DINNER / 8,
      (size_t)BLROWS * 96, nullptr, 0);
  reduce8_k<<<(BLROWS * 96) / 256, 256, 0, stream>>>(xp_p, xp, BLROWS * 96);
  // 6. dt_proj + softplus (fp32)
  gemm_k<1, false><<<dim3(16, 32, 1), 256, 0, stream>>>(
      xp, 96, dt_w, DINNER, delta, DINNER, BLROWS, DINNER, DTRANK, 0, dt_b, 0);
  // 7. chunked scan; p2 writes bf16-split y into xz (z cols untouched)
  scan_p1<<<512, 256, 0, stream>>>(delta, xc, xp, log_A, hend, sumdv);
  scan_mid<<<256, 256, 0, stream>>>(hend, sumdv, log_A, hin);
  scan_p2<<<512, 256, 0, stream>>>(delta, xc, xp, log_A, D_param, hin,
                                   xz + DINNER, yh);
  // 8. transpose+split out_w [2048][1024] -> [1024][2048] (xp_p region now dead)
  tsplit_k<<<dim3(DMODEL / 32, DINNER / 32), 256, 0, stream>>>(out_w, DINNER,
                                                               DMODEL, owh, owl);
  // 9. out_proj: MFMA split-bf16, BM=64 BN=128, grid 8x64, residual fused
  mgemm_k<2, 2, 1, 2, 2><<<dim3(8, 64), 256, 0, stream>>>(
      yh, yl, 8192, owh, owl, DINNER, out, DMODEL, x, DMODEL, DINNER);
}